// Round 7
// baseline (1135.293 us; speedup 1.0000x reference)
//
#include <hip/hip_runtime.h>
#include <stdint.h>

#define N_PTS  16384
#define B_SZ   4
#define K_S    1024   // SAMPLE_NUM
#define K_N    32     // NEIGHBOR_NUM
#define C_FEAT 128
#define NCELL  4096   // 16^3 Hilbert cells

// per-batch ws layout: rxyzw float4[N] | ro u16[N] | inv u16[N]
#define WS_RXYZW_BYTES (N_PTS * 16)
#define WS_RO_OFF      WS_RXYZW_BYTES
#define WS_INV_OFF     (WS_RXYZW_BYTES + N_PTS * 2)
#define WS_PER_B_BYTES (WS_RXYZW_BYTES + N_PTS * 4)   // 327680, %16==0

typedef float f32x2 __attribute__((ext_vector_type(2)));

// ---------------- Threefry-2x32 (JAX-compatible) ----------------
__device__ inline void threefry2x32(uint32_t k0, uint32_t k1,
                                    uint32_t x0, uint32_t x1,
                                    uint32_t& o0, uint32_t& o1) {
  uint32_t ks[3] = {k0, k1, k0 ^ k1 ^ 0x1BD11BDAu};
  const uint32_t rot[2][4] = {{13u, 15u, 26u, 6u}, {17u, 29u, 16u, 24u}};
  x0 += ks[0];
  x1 += ks[1];
#pragma unroll
  for (int i = 0; i < 5; ++i) {
    const uint32_t* r = rot[i & 1];
#pragma unroll
    for (int j = 0; j < 4; ++j) {
      x0 += x1;
      x1 = (x1 << r[j]) | (x1 >> (32u - r[j]));
      x1 ^= x0;
    }
    x0 += ks[(i + 1) % 3];
    x1 += ks[(i + 2) % 3] + (uint32_t)(i + 1);
  }
  o0 = x0;
  o1 = x1;
}

__device__ inline int fps_start_index(int b) {
  uint32_t c0, c1, h0, h1;
  threefry2x32(0u, 42u, 0u, 1u, c0, c1);
  threefry2x32(c0, c1, 0u, (uint32_t)b, h0, h1);
  return (int)((h0 ^ h1) & (uint32_t)(N_PTS - 1));
}

// ---------------- DPP u64 max helpers (VALU pipe, no DS ops) --------------
template <int CTRL>
__device__ inline uint64_t dpp_max_u64(uint64_t k) {
  const int lo = (int)(uint32_t)k;
  const int hi = (int)(uint32_t)(k >> 32);
  // bound_ctrl=true: out-of-range lanes read 0 == identity (all keys > 0)
  const uint32_t slo =
      (uint32_t)__builtin_amdgcn_update_dpp(0, lo, CTRL, 0xF, 0xF, true);
  const uint32_t shi =
      (uint32_t)__builtin_amdgcn_update_dpp(0, hi, CTRL, 0xF, 0xF, true);
  const uint64_t s = ((uint64_t)shi << 32) | slo;
  return s > k ? s : k;
}

__device__ inline uint64_t readlane_u64(uint64_t k, int lane) {
  const uint32_t lo =
      (uint32_t)__builtin_amdgcn_readlane((int)(uint32_t)k, lane);
  const uint32_t hi =
      (uint32_t)__builtin_amdgcn_readlane((int)(uint32_t)(k >> 32), lane);
  return ((uint64_t)hi << 32) | lo;
}

__device__ inline float readlane_f32(float v, int lane) {
  return __uint_as_float(
      (uint32_t)__builtin_amdgcn_readlane(__float_as_int(v), lane));
}

// ---------------- packed dual-f32 (VOP3P) helpers -------------------------
// gfx950 has v_pk_add_f32 / v_pk_mul_f32 but NOT v_pk_min_f32 (r4 compile
// error). min is two scalar v_min_f32. IEEE-exact per component; a+(-b) ==
// __fsub_rn(a,b) bit-exactly. Sequence HW-verified bit-exact in r5/r6.
__device__ inline f32x2 pk_add(f32x2 a, f32x2 b) {
  f32x2 d;
  asm("v_pk_add_f32 %0, %1, %2" : "=v"(d) : "v"(a), "v"(b));
  return d;
}
__device__ inline f32x2 pk_mul(f32x2 a, f32x2 b) {
  f32x2 d;
  asm("v_pk_mul_f32 %0, %1, %2" : "=v"(d) : "v"(a), "v"(b));
  return d;
}
__device__ inline f32x2 pk2_min(f32x2 a, f32x2 b) {
  f32x2 d;
  d.x = fminf(a.x, b.x);
  d.y = fminf(a.y, b.y);
  return d;
}

// ---------------- Hilbert index, 4 bits/dim (Skilling) ----------------
// Bucketing is correctness-neutral (keys carry orig idx; group kernel reads
// original arrays). Hilbert: no jumps between consecutive cells -> tight
// per-thread bboxes.
__device__ inline uint32_t hilbert3d4(uint32_t X0, uint32_t X1, uint32_t X2) {
#pragma unroll
  for (uint32_t Q = 8; Q > 1; Q >>= 1) {
    const uint32_t P = Q - 1;
    if (X0 & Q) X0 ^= P;
    if (X1 & Q) X0 ^= P;
    else { const uint32_t tt = (X0 ^ X1) & P; X0 ^= tt; X1 ^= tt; }
    if (X2 & Q) X0 ^= P;
    else { const uint32_t tt = (X0 ^ X2) & P; X0 ^= tt; X2 ^= tt; }
  }
  X1 ^= X0;
  X2 ^= X1;
  uint32_t tt = 0;
#pragma unroll
  for (uint32_t Q = 8; Q > 1; Q >>= 1)
    if (X2 & Q) tt ^= (Q - 1);
  X0 ^= tt; X1 ^= tt; X2 ^= tt;
  uint32_t key = 0;
#pragma unroll
  for (int l = 3; l >= 0; --l)
    key = (key << 3) | (((X0 >> l) & 1u) << 2) | (((X1 >> l) & 1u) << 1) |
          ((X2 >> l) & 1u);
  return key;  // 0..4095
}

// ---------------- Hilbert bucket sort: one block per batch ----------------
__global__ __launch_bounds__(1024) void bucket_kernel(
    const float* __restrict__ xyz, char* __restrict__ ws) {
  const int b = blockIdx.x;
  const int t = threadIdx.x;
  const float* bx = xyz + (size_t)b * N_PTS * 3;
  char* wsb = ws + (size_t)b * WS_PER_B_BYTES;
  float4* rp = (float4*)wsb;
  unsigned short* ro = (unsigned short*)(wsb + WS_RO_OFF);
  unsigned short* inv = (unsigned short*)(wsb + WS_INV_OFF);

  __shared__ unsigned int cnt[NCELL];    // counts -> exclusive offsets
  __shared__ unsigned int tsum[1024];

#pragma unroll
  for (int j = 0; j < NCELL / 1024; ++j) cnt[t + j * 1024] = 0;
  __syncthreads();

  unsigned short cell[16];
#pragma unroll
  for (int j = 0; j < 16; ++j) {
    const int p = t + j * 1024;  // coalesced
    const float x = bx[p * 3 + 0];
    const float y = bx[p * 3 + 1];
    const float z = bx[p * 3 + 2];
    int ix = (int)(x * 16.0f); ix = ix > 15 ? 15 : (ix < 0 ? 0 : ix);
    int iy = (int)(y * 16.0f); iy = iy > 15 ? 15 : (iy < 0 ? 0 : iy);
    int iz = (int)(z * 16.0f); iz = iz > 15 ? 15 : (iz < 0 ? 0 : iz);
    const uint32_t code = hilbert3d4((uint32_t)ix, (uint32_t)iy, (uint32_t)iz);
    cell[j] = (unsigned short)code;
    atomicAdd(&cnt[code], 1u);
  }
  __syncthreads();

  // exclusive prefix sum over 4096 counts: 4 cells/thread + 1024-scan
  const unsigned int c0 = cnt[t * 4 + 0];
  const unsigned int c1 = cnt[t * 4 + 1];
  const unsigned int c2 = cnt[t * 4 + 2];
  const unsigned int c3 = cnt[t * 4 + 3];
  const unsigned int s4 = c0 + c1 + c2 + c3;
  tsum[t] = s4;
  __syncthreads();
  for (int d = 1; d < 1024; d <<= 1) {
    unsigned int add = (t >= d) ? tsum[t - d] : 0u;
    __syncthreads();
    tsum[t] += add;
    __syncthreads();
  }
  unsigned int run = tsum[t] - s4;  // exclusive base for this thread's cells
  cnt[t * 4 + 0] = run; run += c0;
  cnt[t * 4 + 1] = run; run += c1;
  cnt[t * 4 + 2] = run; run += c2;
  cnt[t * 4 + 3] = run;
  __syncthreads();

  // scatter; intra-cell order nondeterministic but FPS results are invariant:
  // keys carry orig idx (commutative max), and pruned updates are no-ops.
#pragma unroll
  for (int j = 0; j < 16; ++j) {
    const int p = t + j * 1024;
    const unsigned int place = atomicAdd(&cnt[cell[j]], 1u);
    rp[place] = make_float4(bx[p * 3 + 0], bx[p * 3 + 1], bx[p * 3 + 2], 0.f);
    ro[place] = (unsigned short)p;
    inv[p] = (unsigned short)place;
  }
}

// ---------------- Bucketed FPS: one 1024-thread block per batch -----------
// r6 winner structure (u64 DPP reduce + pk update) with ONE change: the
// winner-coord load is replaced by an EARLY candidate gather. Right after
// the wkey ds_read, each lane issues rp[k & 0xFFFF] for its slot's candidate
// (16 distinct addrs, identical across waves -> MSHR-coalesced) BEFORE the
// DPP chain; the winner is slot widx = wre>>10, so its coords arrive via 3
// readlanes with a uniform lane index. The ~250cy L2 latency now overlaps
// the reduce instead of following it. Writer path untouched.
#define FT  1024
#define PPT 16
#define PR  (PPT / 2)

__global__ __launch_bounds__(FT, 4) void fps_kernel(
    const char* __restrict__ ws, float* __restrict__ sample_xyz) {
  const int b = blockIdx.x;
  const int t = threadIdx.x;
  const int lane = t & 63;
  const int wv = t >> 6;  // 0..15
  const char* wsb = ws + (size_t)b * WS_PER_B_BYTES;
  const float4* rp = (const float4*)wsb;
  const unsigned short* ro = (const unsigned short*)(wsb + WS_RO_OFF);
  const unsigned short* inv = (const unsigned short*)(wsb + WS_INV_OFF);

  f32x2 px2[PR], py2[PR], pz2[PR], md2[PR];
  uint32_t klo[PPT];  // precomputed key low word: (~orig:16 | reord:16)
  const int base = t * PPT;
#pragma unroll
  for (int i = 0; i < PR; ++i) {
    const float4 v0 = rp[base + 2 * i + 0];
    const float4 v1 = rp[base + 2 * i + 1];
    px2[i].x = v0.x; px2[i].y = v1.x;
    py2[i].x = v0.y; py2[i].y = v1.y;
    pz2[i].x = v0.z; pz2[i].y = v1.z;
    md2[i].x = __int_as_float(0x7f800000);
    md2[i].y = __int_as_float(0x7f800000);
    klo[2 * i + 0] =
        ((0xFFFFu ^ (uint32_t)ro[base + 2 * i + 0]) << 16) |
        (uint32_t)(base + 2 * i + 0);
    klo[2 * i + 1] =
        ((0xFFFFu ^ (uint32_t)ro[base + 2 * i + 1]) << 16) |
        (uint32_t)(base + 2 * i + 1);
  }
  // tight per-thread bbox (16 Hilbert-contiguous points)
  float bnx = px2[0].x, bXx = px2[0].x, bny = py2[0].x, bXy = py2[0].x,
        bnz = pz2[0].x, bXz = pz2[0].x;
#pragma unroll
  for (int i = 0; i < PR; ++i) {
    bnx = fminf(bnx, fminf(px2[i].x, px2[i].y));
    bXx = fmaxf(bXx, fmaxf(px2[i].x, px2[i].y));
    bny = fminf(bny, fminf(py2[i].x, py2[i].y));
    bXy = fmaxf(bXy, fmaxf(py2[i].x, py2[i].y));
    bnz = fminf(bnz, fminf(pz2[i].x, pz2[i].y));
    bXz = fmaxf(bXz, fmaxf(pz2[i].x, pz2[i].y));
  }

  __shared__ uint64_t wkey[2][FT / 64];
  __shared__ float4 scoord[K_S];  // sample buffer, flushed once at the end

  if (t < FT / 64) {  // seed all 16 slots with the start point (md=+inf-ish)
    const int start = fps_start_index(b);
    const uint32_t sre = (uint32_t)inv[start];  // reordered position
    wkey[0][t] = ((uint64_t)0xFFFFFFFFu << 32) |
                 ((uint64_t)(0xFFFFu ^ (uint32_t)start) << 16) | sre;
  }
  float bestv = __int_as_float(0x7f800000);  // cached lane max(md): force upd
  uint64_t klane = 0;   // cached lane-best key
  uint64_t kwave = 0;   // cached wave-reduced key
  __syncthreads();

  for (int s = 0; s < K_S; ++s) {
    const int rb = s & 1, wb = rb ^ 1;

    // read published keys; IMMEDIATELY issue the 16-candidate coord gather
    // (winner is guaranteed to be one of these). Load overlaps the reduce.
    uint64_t k = wkey[rb][lane & 15];
    const float4 cand = rp[(uint32_t)k & 0xFFFFu];

    // cross-wave argmax: 4 DPP stages + readlane (VALU pipe)
    k = dpp_max_u64<0x111>(k);  // row_shr:1
    k = dpp_max_u64<0x112>(k);  // row_shr:2
    k = dpp_max_u64<0x114>(k);  // row_shr:4
    k = dpp_max_u64<0x118>(k);  // row_shr:8  -> lane15 of each row = max
    const uint64_t best = readlane_u64(k, 15);  // uniform
    const int wre = (int)(best & 0xFFFFu);      // winner's reordered index
    const int widx = wre >> 10;                 // winner slot/wave 0..15

    // winner coords: 3 readlanes (uniform lane index) off the early gather
    const float cx = readlane_f32(cand.x, widx);
    const float cy = readlane_f32(cand.y, widx);
    const float cz = readlane_f32(cand.z, widx);
    if (t == 0) scoord[s] = make_float4(cx, cy, cz, 0.f);

    // conservative squared lower bound to this thread's bbox
    const float dlx = fmaxf(fmaxf(__fsub_rn(bnx, cx), __fsub_rn(cx, bXx)), 0.f);
    const float dly = fmaxf(fmaxf(__fsub_rn(bny, cy), __fsub_rn(cy, bXy)), 0.f);
    const float dlz = fmaxf(fmaxf(__fsub_rn(bnz, cz), __fsub_rn(cz, bXz)), 0.f);
    const float lb = dlx * dlx + dly * dly + dlz * dlz;
    const bool upd = (lb * 0.999f) < bestv;  // exact skip (margin >> rounding)

    if (__any(upd)) {
      if (upd) {
        // packed update: a+(-c) == a-c bit-exactly; XLA order per component
        f32x2 ncx2; ncx2.x = -cx; ncx2.y = -cx;
        f32x2 ncy2; ncy2.x = -cy; ncy2.y = -cy;
        f32x2 ncz2; ncz2.x = -cz; ncz2.y = -cz;
        uint64_t kk0 = 0, kk1 = 0;
#pragma unroll
        for (int i = 0; i < PR; ++i) {
          const f32x2 dx = pk_add(px2[i], ncx2);
          const f32x2 dy = pk_add(py2[i], ncy2);
          const f32x2 dz = pk_add(pz2[i], ncz2);
          const f32x2 sxy = pk_add(pk_mul(dx, dx), pk_mul(dy, dy));
          const f32x2 d2 = pk_add(sxy, pk_mul(dz, dz));
          const f32x2 m = pk2_min(md2[i], d2);
          md2[i] = m;
          const uint64_t key0 =
              ((uint64_t)__float_as_uint(m.x) << 32) | klo[2 * i + 0];
          const uint64_t key1 =
              ((uint64_t)__float_as_uint(m.y) << 32) | klo[2 * i + 1];
          kk0 = key0 > kk0 ? key0 : kk0;
          kk1 = key1 > kk1 ? key1 : kk1;
        }
        const uint64_t kk = kk0 > kk1 ? kk0 : kk1;
        klane = kk;
        bestv = __uint_as_float((uint32_t)(kk >> 32));
      }
      // wave argmax over all 64 lanes' cached keys, pure DPP
      uint64_t r = klane;
      r = dpp_max_u64<0x111>(r);
      r = dpp_max_u64<0x112>(r);
      r = dpp_max_u64<0x114>(r);
      r = dpp_max_u64<0x118>(r);
      r = dpp_max_u64<0x142>(r);  // row_bcast15
      r = dpp_max_u64<0x143>(r);  // row_bcast31 -> lane63 = wave max
      kwave = readlane_u64(r, 63);
    }
    if (lane == 0) wkey[wb][wv] = kwave;
    __syncthreads();  // the one barrier; lgkmcnt-dominated drain
  }

  // flush sample buffer (once)
  {
    const float4 v = scoord[t];
    float* o = sample_xyz + ((size_t)b * K_S + t) * 3;
    o[0] = v.x; o[1] = v.y; o[2] = v.z;
  }
}

// ---------------- Ball query + gather: one wave per query ----------------
__global__ __launch_bounds__(256) void group_kernel(
    const float* __restrict__ xyz, const float* __restrict__ feat,
    const float* __restrict__ sample_xyz, float* __restrict__ out_feat) {
  const int lane = threadIdx.x & 63;
  const int wv = threadIdx.x >> 6;
  const int q = blockIdx.x * 4 + wv;  // 0..4095
  const int b = q >> 10;

  __shared__ int idxs[4][K_N];

  const float qx = sample_xyz[q * 3 + 0];
  const float qy = sample_xyz[q * 3 + 1];
  const float qz = sample_xyz[q * 3 + 2];
  const float* bx = xyz + (size_t)b * N_PTS * 3;
  const float R2 = (float)(0.2 * 0.2);  // f32 round of the Python double
  const unsigned long long below = (1ull << lane) - 1ull;

  int cnt = 0;
  for (int c = 0; c < N_PTS / 128 && cnt < K_N; ++c) {
    const int p0 = c * 128 + lane;
    const int p1 = p0 + 64;
    const float x0 = bx[p0 * 3 + 0], y0 = bx[p0 * 3 + 1], z0 = bx[p0 * 3 + 2];
    const float x1 = bx[p1 * 3 + 0], y1 = bx[p1 * 3 + 1], z1 = bx[p1 * 3 + 2];

    const float dx0 = __fsub_rn(qx, x0), dy0 = __fsub_rn(qy, y0),
                dz0 = __fsub_rn(qz, z0);
    const float d20 = __fadd_rn(
        __fadd_rn(__fmul_rn(dx0, dx0), __fmul_rn(dy0, dy0)),
        __fmul_rn(dz0, dz0));
    const float dx1 = __fsub_rn(qx, x1), dy1 = __fsub_rn(qy, y1),
                dz1 = __fsub_rn(qz, z1);
    const float d21 = __fadd_rn(
        __fadd_rn(__fmul_rn(dx1, dx1), __fmul_rn(dy1, dy1)),
        __fmul_rn(dz1, dz1));

    const bool h0 = d20 < R2;
    const bool h1 = d21 < R2;
    const unsigned long long m0 = __ballot(h0);
    const unsigned long long m1 = __ballot(h1);
    const int c0 = (int)__popcll(m0);
    if (h0) {
      const int slot = cnt + (int)__popcll(m0 & below);
      if (slot < K_N) idxs[wv][slot] = p0;
    }
    if (h1) {
      const int slot = cnt + c0 + (int)__popcll(m1 & below);
      if (slot < K_N) idxs[wv][slot] = p1;
    }
    cnt += c0 + (int)__popcll(m1);
  }
  // -1 padding semantics: gather_feat maps -1 -> row SAMPLE_NUM (=1024)
  if (cnt < K_N) {
    for (int s2 = cnt + lane; s2 < K_N; s2 += 64) idxs[wv][s2] = K_S;
  }
  __syncthreads();

  // gather feat rows -> out[(q*32 + k)*128 + c], float4 coalesced, full unroll
  const float4* f4 = (const float4*)feat;
  float4* o4 = (float4*)out_feat;
  const size_t fbase = (size_t)b * N_PTS * (C_FEAT / 4);
  const size_t obase = (size_t)q * K_N * (C_FEAT / 4);
  const int c4 = lane & 31;
  const int khalf = lane >> 5;
#pragma unroll
  for (int kk = 0; kk < K_N; kk += 2) {
    const int k = kk + khalf;
    const int id = idxs[wv][k];
    const float4 v = f4[fbase + (size_t)id * (C_FEAT / 4) + c4];
    o4[obase + (size_t)k * (C_FEAT / 4) + c4] = v;
  }
}

extern "C" void kernel_launch(void* const* d_in, const int* in_sizes, int n_in,
                              void* d_out, int out_size, void* d_ws,
                              size_t ws_size, hipStream_t stream) {
  const float* xyz = (const float*)d_in[0];
  const float* feat = (const float*)d_in[1];
  float* sample_xyz = (float*)d_out;
  float* out_feat = (float*)d_out + (size_t)B_SZ * K_S * 3;
  char* ws = (char*)d_ws;

  hipLaunchKernelGGL(bucket_kernel, dim3(B_SZ), dim3(1024), 0, stream, xyz, ws);
  hipLaunchKernelGGL(fps_kernel, dim3(B_SZ), dim3(FT), 0, stream, ws,
                     sample_xyz);
  hipLaunchKernelGGL(group_kernel, dim3((B_SZ * K_S) / 4), dim3(256), 0,
                     stream, xyz, feat, sample_xyz, out_feat);
}

// Round 8
// 969.430 us; speedup vs baseline: 1.1711x; 1.1711x over previous
//
#include <hip/hip_runtime.h>
#include <stdint.h>

#define N_PTS  16384
#define B_SZ   4
#define K_S    1024   // SAMPLE_NUM
#define K_N    32     // NEIGHBOR_NUM
#define C_FEAT 128
#define NCELL  4096   // 16^3 Hilbert cells

// per-batch ws layout: rxyzw float4[N] | ro u16[N] | inv u16[N]
#define WS_RXYZW_BYTES (N_PTS * 16)
#define WS_RO_OFF      WS_RXYZW_BYTES
#define WS_INV_OFF     (WS_RXYZW_BYTES + N_PTS * 2)
#define WS_PER_B_BYTES (WS_RXYZW_BYTES + N_PTS * 4)   // 327680, %16==0

typedef float f32x2 __attribute__((ext_vector_type(2)));

// ---------------- Threefry-2x32 (JAX-compatible) ----------------
__device__ inline void threefry2x32(uint32_t k0, uint32_t k1,
                                    uint32_t x0, uint32_t x1,
                                    uint32_t& o0, uint32_t& o1) {
  uint32_t ks[3] = {k0, k1, k0 ^ k1 ^ 0x1BD11BDAu};
  const uint32_t rot[2][4] = {{13u, 15u, 26u, 6u}, {17u, 29u, 16u, 24u}};
  x0 += ks[0];
  x1 += ks[1];
#pragma unroll
  for (int i = 0; i < 5; ++i) {
    const uint32_t* r = rot[i & 1];
#pragma unroll
    for (int j = 0; j < 4; ++j) {
      x0 += x1;
      x1 = (x1 << r[j]) | (x1 >> (32u - r[j]));
      x1 ^= x0;
    }
    x0 += ks[(i + 1) % 3];
    x1 += ks[(i + 2) % 3] + (uint32_t)(i + 1);
  }
  o0 = x0;
  o1 = x1;
}

__device__ inline int fps_start_index(int b) {
  uint32_t c0, c1, h0, h1;
  threefry2x32(0u, 42u, 0u, 1u, c0, c1);
  threefry2x32(c0, c1, 0u, (uint32_t)b, h0, h1);
  return (int)((h0 ^ h1) & (uint32_t)(N_PTS - 1));
}

// ---------------- key max via v_max_f64 -----------------------------------
// Keys are (md_fp32_bits:32 | ~orig:16 | reord:16). High word <= 0x7F800000
// (md finite, <= ~3.0 -> <= 0x40400000; seed uses 0x7F800000), so as f64 both
// operands are non-negative finite -> IEEE max == lexicographic u64 max.
// 1 instruction replaces v_cmp_lt_u64 + 2x v_cndmask.
__device__ inline uint64_t max_key(uint64_t a, uint64_t b) {
  uint64_t d;
  asm("v_max_f64 %0, %1, %2" : "=v"(d) : "v"(a), "v"(b));
  return d;
}

// DPP u64-key max: 2 DPP movs + 1 v_max_f64 (VALU pipe, no DS ops).
// bound_ctrl=true: out-of-range lanes read 0 == +0.0 f64 == identity.
template <int CTRL>
__device__ inline uint64_t dpp_max_u64(uint64_t k) {
  const int lo = (int)(uint32_t)k;
  const int hi = (int)(uint32_t)(k >> 32);
  const uint32_t slo =
      (uint32_t)__builtin_amdgcn_update_dpp(0, lo, CTRL, 0xF, 0xF, true);
  const uint32_t shi =
      (uint32_t)__builtin_amdgcn_update_dpp(0, hi, CTRL, 0xF, 0xF, true);
  const uint64_t s = ((uint64_t)shi << 32) | slo;
  return max_key(s, k);
}

__device__ inline uint64_t readlane_u64(uint64_t k, int lane) {
  const uint32_t lo =
      (uint32_t)__builtin_amdgcn_readlane((int)(uint32_t)k, lane);
  const uint32_t hi =
      (uint32_t)__builtin_amdgcn_readlane((int)(uint32_t)(k >> 32), lane);
  return ((uint64_t)hi << 32) | lo;
}

// ---------------- packed dual-f32 (VOP3P) helpers -------------------------
// gfx950 has v_pk_add_f32 / v_pk_mul_f32 but NOT v_pk_min_f32 (r4 compile
// error). min is two scalar v_min_f32. IEEE-exact per component; a+(-b) ==
// __fsub_rn(a,b) bit-exactly. Sequence HW-verified bit-exact in r5/r6.
__device__ inline f32x2 pk_add(f32x2 a, f32x2 b) {
  f32x2 d;
  asm("v_pk_add_f32 %0, %1, %2" : "=v"(d) : "v"(a), "v"(b));
  return d;
}
__device__ inline f32x2 pk_mul(f32x2 a, f32x2 b) {
  f32x2 d;
  asm("v_pk_mul_f32 %0, %1, %2" : "=v"(d) : "v"(a), "v"(b));
  return d;
}
__device__ inline f32x2 pk2_min(f32x2 a, f32x2 b) {
  f32x2 d;
  d.x = fminf(a.x, b.x);
  d.y = fminf(a.y, b.y);
  return d;
}

// ---------------- Hilbert index, 4 bits/dim (Skilling) ----------------
// Bucketing is correctness-neutral (keys carry orig idx; group kernel reads
// original arrays). Hilbert: no jumps between consecutive cells -> tight
// per-thread bboxes.
__device__ inline uint32_t hilbert3d4(uint32_t X0, uint32_t X1, uint32_t X2) {
#pragma unroll
  for (uint32_t Q = 8; Q > 1; Q >>= 1) {
    const uint32_t P = Q - 1;
    if (X0 & Q) X0 ^= P;
    if (X1 & Q) X0 ^= P;
    else { const uint32_t tt = (X0 ^ X1) & P; X0 ^= tt; X1 ^= tt; }
    if (X2 & Q) X0 ^= P;
    else { const uint32_t tt = (X0 ^ X2) & P; X0 ^= tt; X2 ^= tt; }
  }
  X1 ^= X0;
  X2 ^= X1;
  uint32_t tt = 0;
#pragma unroll
  for (uint32_t Q = 8; Q > 1; Q >>= 1)
    if (X2 & Q) tt ^= (Q - 1);
  X0 ^= tt; X1 ^= tt; X2 ^= tt;
  uint32_t key = 0;
#pragma unroll
  for (int l = 3; l >= 0; --l)
    key = (key << 3) | (((X0 >> l) & 1u) << 2) | (((X1 >> l) & 1u) << 1) |
          ((X2 >> l) & 1u);
  return key;  // 0..4095
}

// ---------------- Hilbert bucket sort: one block per batch ----------------
__global__ __launch_bounds__(1024) void bucket_kernel(
    const float* __restrict__ xyz, char* __restrict__ ws) {
  const int b = blockIdx.x;
  const int t = threadIdx.x;
  const float* bx = xyz + (size_t)b * N_PTS * 3;
  char* wsb = ws + (size_t)b * WS_PER_B_BYTES;
  float4* rp = (float4*)wsb;
  unsigned short* ro = (unsigned short*)(wsb + WS_RO_OFF);
  unsigned short* inv = (unsigned short*)(wsb + WS_INV_OFF);

  __shared__ unsigned int cnt[NCELL];    // counts -> exclusive offsets
  __shared__ unsigned int tsum[1024];

#pragma unroll
  for (int j = 0; j < NCELL / 1024; ++j) cnt[t + j * 1024] = 0;
  __syncthreads();

  unsigned short cell[16];
#pragma unroll
  for (int j = 0; j < 16; ++j) {
    const int p = t + j * 1024;  // coalesced
    const float x = bx[p * 3 + 0];
    const float y = bx[p * 3 + 1];
    const float z = bx[p * 3 + 2];
    int ix = (int)(x * 16.0f); ix = ix > 15 ? 15 : (ix < 0 ? 0 : ix);
    int iy = (int)(y * 16.0f); iy = iy > 15 ? 15 : (iy < 0 ? 0 : iy);
    int iz = (int)(z * 16.0f); iz = iz > 15 ? 15 : (iz < 0 ? 0 : iz);
    const uint32_t code = hilbert3d4((uint32_t)ix, (uint32_t)iy, (uint32_t)iz);
    cell[j] = (unsigned short)code;
    atomicAdd(&cnt[code], 1u);
  }
  __syncthreads();

  // exclusive prefix sum over 4096 counts: 4 cells/thread + 1024-scan
  const unsigned int c0 = cnt[t * 4 + 0];
  const unsigned int c1 = cnt[t * 4 + 1];
  const unsigned int c2 = cnt[t * 4 + 2];
  const unsigned int c3 = cnt[t * 4 + 3];
  const unsigned int s4 = c0 + c1 + c2 + c3;
  tsum[t] = s4;
  __syncthreads();
  for (int d = 1; d < 1024; d <<= 1) {
    unsigned int add = (t >= d) ? tsum[t - d] : 0u;
    __syncthreads();
    tsum[t] += add;
    __syncthreads();
  }
  unsigned int run = tsum[t] - s4;  // exclusive base for this thread's cells
  cnt[t * 4 + 0] = run; run += c0;
  cnt[t * 4 + 1] = run; run += c1;
  cnt[t * 4 + 2] = run; run += c2;
  cnt[t * 4 + 3] = run;
  __syncthreads();

  // scatter; intra-cell order nondeterministic but FPS results are invariant:
  // keys carry orig idx (commutative max), and pruned updates are no-ops.
#pragma unroll
  for (int j = 0; j < 16; ++j) {
    const int p = t + j * 1024;
    const unsigned int place = atomicAdd(&cnt[cell[j]], 1u);
    rp[place] = make_float4(bx[p * 3 + 0], bx[p * 3 + 1], bx[p * 3 + 2], 0.f);
    ro[place] = (unsigned short)p;
    inv[p] = (unsigned short)place;
  }
}

// ---------------- Bucketed FPS: one 1024-thread block per batch -----------
// r6 structure (best so far, 915us): u64 DPP reduce + pk update + ONE uniform
// rp[wre] winner-coord load (3 alternatives all regressed: r1/r5 LDS mirror
// +940us, r7 early per-lane gather +85us -- the uniform load stays).
// This round: every u64 key max via v_max_f64 (1 inst, bit-equivalent for
// our non-negative-f64-pattern keys) instead of cmp+2cndmask.
#define FT  1024
#define PPT 16
#define PR  (PPT / 2)

__global__ __launch_bounds__(FT, 4) void fps_kernel(
    const char* __restrict__ ws, float* __restrict__ sample_xyz) {
  const int b = blockIdx.x;
  const int t = threadIdx.x;
  const int lane = t & 63;
  const int wv = t >> 6;  // 0..15
  const char* wsb = ws + (size_t)b * WS_PER_B_BYTES;
  const float4* rp = (const float4*)wsb;
  const unsigned short* ro = (const unsigned short*)(wsb + WS_RO_OFF);
  const unsigned short* inv = (const unsigned short*)(wsb + WS_INV_OFF);

  f32x2 px2[PR], py2[PR], pz2[PR], md2[PR];
  uint32_t klo[PPT];  // precomputed key low word: (~orig:16 | reord:16)
  const int base = t * PPT;
#pragma unroll
  for (int i = 0; i < PR; ++i) {
    const float4 v0 = rp[base + 2 * i + 0];
    const float4 v1 = rp[base + 2 * i + 1];
    px2[i].x = v0.x; px2[i].y = v1.x;
    py2[i].x = v0.y; py2[i].y = v1.y;
    pz2[i].x = v0.z; pz2[i].y = v1.z;
    md2[i].x = __int_as_float(0x7f800000);
    md2[i].y = __int_as_float(0x7f800000);
    klo[2 * i + 0] =
        ((0xFFFFu ^ (uint32_t)ro[base + 2 * i + 0]) << 16) |
        (uint32_t)(base + 2 * i + 0);
    klo[2 * i + 1] =
        ((0xFFFFu ^ (uint32_t)ro[base + 2 * i + 1]) << 16) |
        (uint32_t)(base + 2 * i + 1);
  }
  // tight per-thread bbox (16 Hilbert-contiguous points)
  float bnx = px2[0].x, bXx = px2[0].x, bny = py2[0].x, bXy = py2[0].x,
        bnz = pz2[0].x, bXz = pz2[0].x;
#pragma unroll
  for (int i = 0; i < PR; ++i) {
    bnx = fminf(bnx, fminf(px2[i].x, px2[i].y));
    bXx = fmaxf(bXx, fmaxf(px2[i].x, px2[i].y));
    bny = fminf(bny, fminf(py2[i].x, py2[i].y));
    bXy = fmaxf(bXy, fmaxf(py2[i].x, py2[i].y));
    bnz = fminf(bnz, fminf(pz2[i].x, pz2[i].y));
    bXz = fmaxf(bXz, fmaxf(pz2[i].x, pz2[i].y));
  }

  __shared__ uint64_t wkey[2][FT / 64];
  __shared__ float4 scoord[K_S];  // sample buffer, flushed once at the end

  if (t < FT / 64) {  // seed all 16 slots with the start point.
    // Seed high word = 0x7F800000 (fp32 +inf bits): beats every real key
    // (md <= ~3.0 -> bits <= 0x40400000) and is a FINITE positive f64
    // pattern (exponent field 0x7F8 != 0x7FF) -> safe for v_max_f64.
    const int start = fps_start_index(b);
    const uint32_t sre = (uint32_t)inv[start];  // reordered position
    wkey[0][t] = ((uint64_t)0x7F800000u << 32) |
                 ((uint64_t)(0xFFFFu ^ (uint32_t)start) << 16) | sre;
  }
  float bestv = __int_as_float(0x7f800000);  // cached lane max(md): force upd
  uint64_t klane = 0;   // cached lane-best key
  uint64_t kwave = 0;   // cached wave-reduced key
  __syncthreads();

  for (int s = 0; s < K_S; ++s) {
    const int rb = s & 1, wb = rb ^ 1;

    // cross-wave argmax: 1 DS read + 4 DPP stages + readlane (VALU pipe)
    uint64_t k = wkey[rb][lane & 15];
    k = dpp_max_u64<0x111>(k);  // row_shr:1
    k = dpp_max_u64<0x112>(k);  // row_shr:2
    k = dpp_max_u64<0x114>(k);  // row_shr:4
    k = dpp_max_u64<0x118>(k);  // row_shr:8  -> lane15 of each row = max
    const uint64_t best = readlane_u64(k, 15);  // uniform
    const int wre = (int)(best & 0xFFFFu);      // winner's reordered index

    // uniform winner-coord load (MSHR-coalesced L2 broadcast; keep this)
    const float4 c = rp[wre];
    if (t == 0) scoord[s] = c;
    const float cx = c.x, cy = c.y, cz = c.z;

    // conservative squared lower bound to this thread's bbox
    const float dlx = fmaxf(fmaxf(__fsub_rn(bnx, cx), __fsub_rn(cx, bXx)), 0.f);
    const float dly = fmaxf(fmaxf(__fsub_rn(bny, cy), __fsub_rn(cy, bXy)), 0.f);
    const float dlz = fmaxf(fmaxf(__fsub_rn(bnz, cz), __fsub_rn(cz, bXz)), 0.f);
    const float lb = dlx * dlx + dly * dly + dlz * dlz;
    const bool upd = (lb * 0.999f) < bestv;  // exact skip (margin >> rounding)

    if (__any(upd)) {
      if (upd) {
        // packed update: a+(-c) == a-c bit-exactly; XLA order per component
        f32x2 ncx2; ncx2.x = -cx; ncx2.y = -cx;
        f32x2 ncy2; ncy2.x = -cy; ncy2.y = -cy;
        f32x2 ncz2; ncz2.x = -cz; ncz2.y = -cz;
        uint64_t kk0 = 0, kk1 = 0;
#pragma unroll
        for (int i = 0; i < PR; ++i) {
          const f32x2 dx = pk_add(px2[i], ncx2);
          const f32x2 dy = pk_add(py2[i], ncy2);
          const f32x2 dz = pk_add(pz2[i], ncz2);
          const f32x2 sxy = pk_add(pk_mul(dx, dx), pk_mul(dy, dy));
          const f32x2 d2 = pk_add(sxy, pk_mul(dz, dz));
          const f32x2 m = pk2_min(md2[i], d2);
          md2[i] = m;
          const uint64_t key0 =
              ((uint64_t)__float_as_uint(m.x) << 32) | klo[2 * i + 0];
          const uint64_t key1 =
              ((uint64_t)__float_as_uint(m.y) << 32) | klo[2 * i + 1];
          kk0 = max_key(kk0, key0);
          kk1 = max_key(kk1, key1);
        }
        klane = max_key(kk0, kk1);
        bestv = __uint_as_float((uint32_t)(klane >> 32));
      }
      // wave argmax over all 64 lanes' cached keys, pure DPP
      uint64_t r = klane;
      r = dpp_max_u64<0x111>(r);
      r = dpp_max_u64<0x112>(r);
      r = dpp_max_u64<0x114>(r);
      r = dpp_max_u64<0x118>(r);
      r = dpp_max_u64<0x142>(r);  // row_bcast15
      r = dpp_max_u64<0x143>(r);  // row_bcast31 -> lane63 = wave max
      kwave = readlane_u64(r, 63);
    }
    if (lane == 0) wkey[wb][wv] = kwave;
    __syncthreads();  // the one barrier; lgkmcnt-dominated drain
  }

  // flush sample buffer (once)
  {
    const float4 v = scoord[t];
    float* o = sample_xyz + ((size_t)b * K_S + t) * 3;
    o[0] = v.x; o[1] = v.y; o[2] = v.z;
  }
}

// ---------------- Ball query + gather: one wave per query ----------------
__global__ __launch_bounds__(256) void group_kernel(
    const float* __restrict__ xyz, const float* __restrict__ feat,
    const float* __restrict__ sample_xyz, float* __restrict__ out_feat) {
  const int lane = threadIdx.x & 63;
  const int wv = threadIdx.x >> 6;
  const int q = blockIdx.x * 4 + wv;  // 0..4095
  const int b = q >> 10;

  __shared__ int idxs[4][K_N];

  const float qx = sample_xyz[q * 3 + 0];
  const float qy = sample_xyz[q * 3 + 1];
  const float qz = sample_xyz[q * 3 + 2];
  const float* bx = xyz + (size_t)b * N_PTS * 3;
  const float R2 = (float)(0.2 * 0.2);  // f32 round of the Python double
  const unsigned long long below = (1ull << lane) - 1ull;

  int cnt = 0;
  for (int c = 0; c < N_PTS / 128 && cnt < K_N; ++c) {
    const int p0 = c * 128 + lane;
    const int p1 = p0 + 64;
    const float x0 = bx[p0 * 3 + 0], y0 = bx[p0 * 3 + 1], z0 = bx[p0 * 3 + 2];
    const float x1 = bx[p1 * 3 + 0], y1 = bx[p1 * 3 + 1], z1 = bx[p1 * 3 + 2];

    const float dx0 = __fsub_rn(qx, x0), dy0 = __fsub_rn(qy, y0),
                dz0 = __fsub_rn(qz, z0);
    const float d20 = __fadd_rn(
        __fadd_rn(__fmul_rn(dx0, dx0), __fmul_rn(dy0, dy0)),
        __fmul_rn(dz0, dz0));
    const float dx1 = __fsub_rn(qx, x1), dy1 = __fsub_rn(qy, y1),
                dz1 = __fsub_rn(qz, z1);
    const float d21 = __fadd_rn(
        __fadd_rn(__fmul_rn(dx1, dx1), __fmul_rn(dy1, dy1)),
        __fmul_rn(dz1, dz1));

    const bool h0 = d20 < R2;
    const bool h1 = d21 < R2;
    const unsigned long long m0 = __ballot(h0);
    const unsigned long long m1 = __ballot(h1);
    const int c0 = (int)__popcll(m0);
    if (h0) {
      const int slot = cnt + (int)__popcll(m0 & below);
      if (slot < K_N) idxs[wv][slot] = p0;
    }
    if (h1) {
      const int slot = cnt + c0 + (int)__popcll(m1 & below);
      if (slot < K_N) idxs[wv][slot] = p1;
    }
    cnt += c0 + (int)__popcll(m1);
  }
  // -1 padding semantics: gather_feat maps -1 -> row SAMPLE_NUM (=1024)
  if (cnt < K_N) {
    for (int s2 = cnt + lane; s2 < K_N; s2 += 64) idxs[wv][s2] = K_S;
  }
  __syncthreads();

  // gather feat rows -> out[(q*32 + k)*128 + c], float4 coalesced, full unroll
  const float4* f4 = (const float4*)feat;
  float4* o4 = (float4*)out_feat;
  const size_t fbase = (size_t)b * N_PTS * (C_FEAT / 4);
  const size_t obase = (size_t)q * K_N * (C_FEAT / 4);
  const int c4 = lane & 31;
  const int khalf = lane >> 5;
#pragma unroll
  for (int kk = 0; kk < K_N; kk += 2) {
    const int k = kk + khalf;
    const int id = idxs[wv][k];
    const float4 v = f4[fbase + (size_t)id * (C_FEAT / 4) + c4];
    o4[obase + (size_t)k * (C_FEAT / 4) + c4] = v;
  }
}

extern "C" void kernel_launch(void* const* d_in, const int* in_sizes, int n_in,
                              void* d_out, int out_size, void* d_ws,
                              size_t ws_size, hipStream_t stream) {
  const float* xyz = (const float*)d_in[0];
  const float* feat = (const float*)d_in[1];
  float* sample_xyz = (float*)d_out;
  float* out_feat = (float*)d_out + (size_t)B_SZ * K_S * 3;
  char* ws = (char*)d_ws;

  hipLaunchKernelGGL(bucket_kernel, dim3(B_SZ), dim3(1024), 0, stream, xyz, ws);
  hipLaunchKernelGGL(fps_kernel, dim3(B_SZ), dim3(FT), 0, stream, ws,
                     sample_xyz);
  hipLaunchKernelGGL(group_kernel, dim3((B_SZ * K_S) / 4), dim3(256), 0,
                     stream, xyz, feat, sample_xyz, out_feat);
}